// Round 2
// baseline (307.266 us; speedup 1.0000x reference)
//
#include <hip/hip_runtime.h>

// QuaternionLinear as GEMM: M=32768 (batch), N=1024 (OUT_F*4), K=1024 (IN_F*4).
// W_eff[4o+r][4i+c] = sign(r,c) * weight[o][i][r^c], built in d_ws as bf16.
//
// R5: R4's 8-phase port hit 86.7us / MfmaUtil 32% — phase arithmetic shows
// 620 cyc of MFMA inside 1630-cyc phases: the 2-barriers-PER-PHASE convoy
// serializes LDS-read time and MFMA time at block scope. Fix: quad structure,
// 2 barriers per K-TILE (4x fewer): read ALL fragments of the resident tile
// up front (bf + af q0/q1, then af q2/q3 mid-quad), let the compiler's counted
// lgkmcnt overlap reads with MFMA, stage A(kt+1) early / B(kt+2) after BAR1
// (operand-dependence of MFMA q0 proves bf retired before the Bs overwrite),
// counted vmcnt(4) once per quad. sched_barrier(0) pins MFMA clusters before
// each s_barrier (rule: MFMA is register-only, otherwise sinkable past asm).
// Keeps verified XOR bank swizzle (conflicts==0), XCD-aware bijective grid
// swizzle, MFMA fragment mapping and epilogue. build_weff+conv_x merged into
// one prep launch.

typedef __bf16 bf16x8_t __attribute__((ext_vector_type(8)));
typedef short short8    __attribute__((ext_vector_type(8)));
typedef float f32x4     __attribute__((ext_vector_type(4)));
typedef float f32x8     __attribute__((ext_vector_type(8)));

typedef const unsigned int __attribute__((address_space(1)))* gas_uint_ptr;
typedef unsigned int __attribute__((address_space(3)))*       las_uint_ptr;

__device__ __forceinline__ void weff_body(const float* __restrict__ w,
                                          unsigned short* __restrict__ wq,
                                          int idx) {
    const int n = idx >> 10, k = idx & 1023;
    const int o = n >> 2, r = n & 3, i = k >> 2, cc = k & 3;
    const int s = r ^ cc;
    float v = w[o * 1024 + i * 4 + s];
    if ((0x284E >> (r * 4 + cc)) & 1) v = -v;
    union { __bf16 b; unsigned short u; } cv;
    cv.b = (__bf16)v;
    wq[idx] = cv.u;
}

// ---------------------------------------------------------------------------
// Prep (fused): blocks [0,16384) stream-convert x fp32->bf16 (33.5M elems);
// blocks [16384,20480) build W_eff bf16 (1024x1024).
// ---------------------------------------------------------------------------
__global__ __launch_bounds__(256) void prep(const float* __restrict__ x,
                                            unsigned short* __restrict__ xb,
                                            const float* __restrict__ w,
                                            unsigned short* __restrict__ wq) {
    const int b = blockIdx.x;
    if (b < 16384) {
        const long long c = (long long)b * 256 + threadIdx.x;   // 8-elem chunk
        const float* gp = x + c * 8;
        f32x4 lo = *(const f32x4*)gp;
        f32x4 hi = *(const f32x4*)(gp + 4);
        f32x8 f8 = __builtin_shufflevector(lo, hi, 0, 1, 2, 3, 4, 5, 6, 7);
        bf16x8_t bv = __builtin_convertvector(f8, bf16x8_t);
        union { bf16x8_t b; short8 s; } cv;
        cv.b = bv;
        *(short8*)(xb + c * 8) = cv.s;
    } else {
        weff_body(w, wq, (b - 16384) * 256 + threadIdx.x);
    }
}

__global__ __launch_bounds__(256) void build_weff(const float* __restrict__ w,
                                                  unsigned short* __restrict__ wq) {
    weff_body(w, wq, blockIdx.x * 256 + threadIdx.x);
}

// ---------------------------------------------------------------------------
// Quad-structure 256x256 GEMM. Grid = 512 blocks x 512 threads (8 waves,
// 2M x 4N). Per wave: 128x64 output = acc[8][4] f32x4. BK=64, 16 K-tiles.
//
// LDS: As/Bs[par][half][128*64] bf16, 128 KiB total. Swizzle: 16B chunk g of
// row r lives at slot g^(r&7); global_load_lds SOURCE is permuted, dest linear.
//
// Per-quad (K-tile kt, par = kt&1; invariant at entry: tile kt published,
// B(kt+1) in flight = 4 loads):
//   read bf(8) + af_q0,q1(8); stage A(kt+1) [As[par^1], protected by prev
//   publish barrier]; MFMA q0; sched_barrier; BAR1
//   [BAR1 + q0's operand dependence => every wave's bf reads retired]
//   stage B(kt+2) [Bs[par], safe]; read af_q2,q3(8) [As[par], no writer];
//   MFMA q1,q2,q3; sched_barrier; vmcnt(4) [drains A(kt+1),B(kt); leaves
//   B(kt+2)]; BAR2 = publish tile kt+1.
// Last quads clamp (kt&15): harmless re-stage, uniform vmcnt ledger.
// vmcnt(0) after loop: no outstanding LDS-DMA at wave exit.
// ---------------------------------------------------------------------------
__global__ __launch_bounds__(512, 2) void qlin_gemm_quad(
        const unsigned short* __restrict__ Xb,
        const unsigned short* __restrict__ Wq,
        const float* __restrict__ bias,
        float* __restrict__ out) {
    __shared__ __align__(16) unsigned short As[2][2][128 * 64];   // 64 KiB
    __shared__ __align__(16) unsigned short Bs[2][2][128 * 64];   // 64 KiB

    const int t    = threadIdx.x;
    const int w    = t >> 6;
    const int l    = t & 63;
    const int lo16 = l & 15;
    const int hi2  = l >> 4;

    const int bid     = blockIdx.x;
    const int xcd     = bid & 7;                 // HW round-robins XCDs
    const int logical = xcd * 64 + (bid >> 3);   // contiguous chunk per XCD
    const int m0      = (logical >> 2) * 256;    // 4 n-tiles share an A panel
    const int n0      = (logical & 3) * 256;

    const int wm  = (w >> 2) * 128;              // 0 / 128
    const int wn  = (w & 3) * 64;                // 0 / 64 / 128 / 192
    const int hA  = wm >> 7;                     // A half read by this wave
    const int hB  = wn >> 7;                     // B half read by this wave
    const int rbB = wn & 64;                     // B row base within half

    f32x4 acc[8][4] = {};
    short8 afq[4][2][2];                         // [quad][mi][slot]
    short8 bf[4][2];                             // [nt][slot]

    // lane-constant swizzled slot for k-slice ks: (ks*4 + hi2) ^ (lo16 & 7)
    const int sw    = lo16 & 7;
    const int slot0 = hi2 ^ sw;
    const int slot1 = (4 + hi2) ^ sw;

#define STAGE_A(KT, H) do {                                                     \
        const int kk_ = ((KT) & 15) * 64;                                       \
        _Pragma("unroll")                                                       \
        for (int jj = 0; jj < 2; ++jj) {                                        \
            const int idx_ = jj * 512 + t;                                      \
            const int row_ = idx_ >> 3;                                         \
            const int g_   = (idx_ & 7) ^ (row_ & 7);                           \
            const unsigned short* ga_ =                                         \
                Xb + (long long)(m0 + (H) * 128 + row_) * 1024 + kk_ + g_ * 8;  \
            __builtin_amdgcn_global_load_lds((gas_uint_ptr)ga_,                 \
                (las_uint_ptr)(&As[(KT) & 1][(H)][idx_ * 8]), 16, 0, 0);        \
        }                                                                       \
    } while (0)

#define STAGE_B(KT, H) do {                                                     \
        const int kk_ = ((KT) & 15) * 64;                                       \
        _Pragma("unroll")                                                       \
        for (int jj = 0; jj < 2; ++jj) {                                        \
            const int idx_ = jj * 512 + t;                                      \
            const int row_ = idx_ >> 3;                                         \
            const int g_   = (idx_ & 7) ^ (row_ & 7);                           \
            const unsigned short* gb_ =                                         \
                Wq + (n0 + (H) * 128 + row_) * 1024 + kk_ + g_ * 8;             \
            __builtin_amdgcn_global_load_lds((gas_uint_ptr)gb_,                 \
                (las_uint_ptr)(&Bs[(KT) & 1][(H)][idx_ * 8]), 16, 0, 0);        \
        }                                                                       \
    } while (0)

#define READ_BF(PAR) do {                                                       \
        _Pragma("unroll")                                                       \
        for (int nt = 0; nt < 4; ++nt) {                                        \
            const int rl_ = rbB + nt * 16 + lo16;                               \
            bf[nt][0] = *(const short8*)(&Bs[(PAR)][hB][rl_ * 64 + slot0 * 8]); \
            bf[nt][1] = *(const short8*)(&Bs[(PAR)][hB][rl_ * 64 + slot1 * 8]); \
        }                                                                       \
    } while (0)

#define READ_AFQ(PAR, Q) do {                                                   \
        _Pragma("unroll")                                                       \
        for (int mi = 0; mi < 2; ++mi) {                                        \
            const int rl_ = ((Q) * 2 + mi) * 16 + lo16;                         \
            afq[(Q)][mi][0] =                                                   \
                *(const short8*)(&As[(PAR)][hA][rl_ * 64 + slot0 * 8]);         \
            afq[(Q)][mi][1] =                                                   \
                *(const short8*)(&As[(PAR)][hA][rl_ * 64 + slot1 * 8]);         \
        }                                                                       \
    } while (0)

#define MFMA_Q(Q) do {                                                          \
        _Pragma("unroll")                                                       \
        for (int mi = 0; mi < 2; ++mi)                                          \
            _Pragma("unroll")                                                   \
            for (int nt = 0; nt < 4; ++nt) {                                    \
                acc[(Q) * 2 + mi][nt] = __builtin_amdgcn_mfma_f32_16x16x32_bf16(\
                    afq[(Q)][mi][0], bf[nt][0], acc[(Q) * 2 + mi][nt], 0, 0, 0);\
                acc[(Q) * 2 + mi][nt] = __builtin_amdgcn_mfma_f32_16x16x32_bf16(\
                    afq[(Q)][mi][1], bf[nt][1], acc[(Q) * 2 + mi][nt], 0, 0, 0);\
            }                                                                   \
    } while (0)

    // Prologue: stage B0, A0, B1 (12 loads); drain oldest 8 (B0+A0), leaving
    // B1 in flight; publish tile 0.
    STAGE_B(0, 0); STAGE_B(0, 1);
    STAGE_A(0, 0); STAGE_A(0, 1);
    STAGE_B(1, 0); STAGE_B(1, 1);
    asm volatile("s_waitcnt vmcnt(4)" ::: "memory");
    asm volatile("s_barrier" ::: "memory");

    for (int kt = 0; kt < 16; ++kt) {
        const int par = kt & 1;

        READ_BF(par);
        READ_AFQ(par, 0);
        READ_AFQ(par, 1);
        STAGE_A(kt + 1, 0);
        STAGE_A(kt + 1, 1);

        __builtin_amdgcn_s_setprio(1);
        MFMA_Q(0);
        __builtin_amdgcn_s_setprio(0);
        __builtin_amdgcn_sched_barrier(0);          // pin q0 before BAR1
        asm volatile("s_barrier" ::: "memory");     // BAR1

        STAGE_B(kt + 2, 0);
        STAGE_B(kt + 2, 1);
        READ_AFQ(par, 2);
        READ_AFQ(par, 3);

        __builtin_amdgcn_s_setprio(1);
        MFMA_Q(1);
        MFMA_Q(2);
        MFMA_Q(3);
        __builtin_amdgcn_s_setprio(0);
        __builtin_amdgcn_sched_barrier(0);          // pin q1-q3 before publish
        asm volatile("s_waitcnt vmcnt(4)" ::: "memory");
        asm volatile("s_barrier" ::: "memory");     // BAR2 = publish kt+1
    }
    asm volatile("s_waitcnt vmcnt(0)" ::: "memory"); // no DMA past wave exit

#undef STAGE_A
#undef STAGE_B
#undef READ_BF
#undef READ_AFQ
#undef MFMA_Q

    // Epilogue: C/D layout col(n) = lane&15, row(m) = (lane>>4)*4 + reg.
#pragma unroll
    for (int nt = 0; nt < 4; ++nt) {
        const int n  = n0 + wn + nt * 16 + lo16;
        const float bv = bias[n];
#pragma unroll
        for (int mt = 0; mt < 8; ++mt) {
            const int mb = m0 + wm + mt * 16 + hi2 * 4;
#pragma unroll
            for (int r = 0; r < 4; ++r)
                out[(long long)(mb + r) * 1024 + n] = acc[mt][nt][r] + bv;
        }
    }
}

// ---------------------------------------------------------------------------
// Fallback GEMM (R2): fused fp32->bf16 A staging, 128^2 tile. Used only if
// the workspace is too small for the bf16 x copy.
// ---------------------------------------------------------------------------
__global__ __launch_bounds__(256) void qlin_gemm_fused(const float* __restrict__ X,
                                                       const unsigned short* __restrict__ Wq,
                                                       const float* __restrict__ bias,
                                                       float* __restrict__ out) {
    __shared__ __align__(16) unsigned short As[128 * 64];
    __shared__ __align__(16) unsigned short Bs[128 * 64];

    const int t    = threadIdx.x;
    const int w    = t >> 6;
    const int l    = t & 63;
    const int lo16 = l & 15;
    const int hi2  = l >> 4;
    const int bid  = blockIdx.x;
    const int xcd  = bid & 7;
    const int s    = bid >> 3;
    const int m0   = (xcd * 32 + (s >> 3)) * 128;
    const int n0   = (s & 7) * 128;
    const int wm   = (w & 1) * 64;
    const int wn   = (w >> 1) * 64;

    f32x4 acc[4][4] = {};

    for (int kt = 0; kt < 16; ++kt) {
        const int k0 = kt * 64;
        __syncthreads();
#pragma unroll
        for (int jj = 0; jj < 4; ++jj) {
            const int p    = jj * 256 + t;
            const int row  = p >> 3;
            const int g    = (p & 7) ^ (row & 7);
            const unsigned short* gp = Wq + (n0 + row) * 1024 + k0 + g * 8;
            __builtin_amdgcn_global_load_lds((gas_uint_ptr)gp,
                                             (las_uint_ptr)(Bs + p * 8), 16, 0, 0);
        }
#pragma unroll
        for (int jj = 0; jj < 4; ++jj) {
            const int c    = jj * 256 + t;
            const int row  = c >> 3;
            const int g    = c & 7;
            const float* gp = X + (long long)(m0 + row) * 1024 + k0 + g * 8;
            f32x4 lo = *(const f32x4*)gp;
            f32x4 hi = *(const f32x4*)(gp + 4);
            f32x8 f8 = __builtin_shufflevector(lo, hi, 0, 1, 2, 3, 4, 5, 6, 7);
            bf16x8_t bv = __builtin_convertvector(f8, bf16x8_t);
            union { bf16x8_t b; short8 s; } cv;
            cv.b = bv;
            const int p = row * 8 + (g ^ (row & 7));
            *(short8*)(As + p * 8) = cv.s;
        }
        __syncthreads();
#pragma unroll
        for (int ks = 0; ks < 2; ++ks) {
            const int g = ks * 4 + hi2;
            short8 af[4], bfr[4];
#pragma unroll
            for (int mt = 0; mt < 4; ++mt) {
                const int r = wm + mt * 16 + lo16;
                af[mt] = *(const short8*)(As + (r * 8 + (g ^ (r & 7))) * 8);
            }
#pragma unroll
            for (int nt = 0; nt < 4; ++nt) {
                const int r = wn + nt * 16 + lo16;
                bfr[nt] = *(const short8*)(Bs + (r * 8 + (g ^ (r & 7))) * 8);
            }
#pragma unroll
            for (int mt = 0; mt < 4; ++mt)
#pragma unroll
                for (int nt = 0; nt < 4; ++nt)
                    acc[mt][nt] = __builtin_amdgcn_mfma_f32_16x16x32_bf16(
                        af[mt], bfr[nt], acc[mt][nt], 0, 0, 0);
        }
    }

#pragma unroll
    for (int nt = 0; nt < 4; ++nt) {
        const int n  = n0 + wn + nt * 16 + lo16;
        const float bv = bias[n];
#pragma unroll
        for (int mt = 0; mt < 4; ++mt) {
            const int mb = m0 + wm + mt * 16 + hi2 * 4;
#pragma unroll
            for (int r = 0; r < 4; ++r)
                out[(long long)(mb + r) * 1024 + n] = acc[mt][nt][r] + bv;
        }
    }
}

// ---------------------------------------------------------------------------
extern "C" void kernel_launch(void* const* d_in, const int* in_sizes, int n_in,
                              void* d_out, int out_size, void* d_ws, size_t ws_size,
                              hipStream_t stream) {
    const float* x  = (const float*)d_in[0];   // (32768, 256, 4) fp32
    const float* wt = (const float*)d_in[1];   // (256, 256, 4) fp32
    const float* bs = (const float*)d_in[2];   // (256, 4) fp32
    float* out = (float*)d_out;                // (32768, 256, 4) fp32

    unsigned short* wq = (unsigned short*)d_ws;            // 2 MiB W_eff bf16
    const size_t WQ_BYTES = 1024ull * 1024 * 2;
    const size_t XB_BYTES = 32768ull * 1024 * 2;           // 64 MiB x bf16

    if (ws_size >= WQ_BYTES + XB_BYTES) {
        unsigned short* xb = (unsigned short*)((char*)d_ws + WQ_BYTES);
        prep<<<20480, 256, 0, stream>>>(x, xb, wt, wq);    // conv + weff fused
        qlin_gemm_quad<<<512, 512, 0, stream>>>(xb, wq, bs, out);
    } else {
        build_weff<<<4096, 256, 0, stream>>>(wt, wq);
        qlin_gemm_fused<<<2048, 256, 0, stream>>>(x, wq, bs, out);
    }

    (void)in_sizes; (void)n_in; (void)out_size;
}